// Round 2
// baseline (1071.941 us; speedup 1.0000x reference)
//
#include <hip/hip_runtime.h>

// Problem constants (from reference)
constexpr int N_NODES = 100000;
constexpr int N_EDGES = 1000000;
constexpr int D_NODE  = 64;
constexpr int D_EDGE  = 32;
constexpr int D_GLOB  = 32;
constexpr int OUT_DIM = 64;
constexpr int K1 = 2*D_NODE + D_EDGE + D_GLOB; // 192
constexpr int K2 = D_NODE + OUT_DIM + D_GLOB;  // 160

typedef _Float16 f16x8 __attribute__((ext_vector_type(8)));
typedef unsigned short ushort8_t __attribute__((ext_vector_type(8)));
typedef float floatx16 __attribute__((ext_vector_type(16)));

// LDS feature-tile row stride (f16 elems): 400 B rows, 16B-aligned;
// dword bank base per row = 100*row % 32 = 4*row -> A-frag b128 reads are
// 2-way bank aliased (free, per m136).
constexpr int FS = 200;

// d_ws layout (bytes), all 16B-aligned:
//   [0,     24576)  W1t f16 [64][192]   (transposed: [n][k])
//   [24576, 45056)  W2t f16 [64][160]
//   [45056, 46080)  ub  f16 [16][32]
//   [46080, ...  )  xb  f16 [100000][64]  (12.8 MB)
// agg (f16 [100000][64]) lives INSIDE d_out: row n occupies the first
// 128 B of out row n (256 B). Block-exclusive in node_kernel -> no race.
constexpr size_t WS_W1T = 0;
constexpr size_t WS_W2T = 24576;
constexpr size_t WS_UB  = 45056;
constexpr size_t WS_XB  = 46080;

__device__ inline unsigned pack_f2(float a, float b) {
    auto h = __builtin_amdgcn_cvt_pkrtz(a, b);    // v_cvt_pkrtz_f16_f32
    return __builtin_bit_cast(unsigned, h);
}

// ---------------------------------------------------------------------------
// Prep: f16-convert x, u; f16+transpose W1, W2 into d_ws. Runs every launch
// (harness re-poisons d_ws).
// ---------------------------------------------------------------------------
__global__ __launch_bounds__(256) void prep_kernel(
    const float* __restrict__ x, const float* __restrict__ u,
    const float* __restrict__ W1, const float* __restrict__ W2,
    unsigned short* __restrict__ ws_w1t, unsigned short* __restrict__ ws_w2t,
    unsigned short* __restrict__ ws_ub, unsigned short* __restrict__ ws_xb)
{
    const int t = blockIdx.x * 256 + threadIdx.x;
    const int stride = gridDim.x * 256;
    const float4* x4 = (const float4*)x;
    for (int i = t; i < N_NODES * 16; i += stride) {       // x: 1.6M float4
        float4 v = x4[i];
        uint2 pk;
        pk.x = pack_f2(v.x, v.y);
        pk.y = pack_f2(v.z, v.w);
        *(uint2*)&ws_xb[i * 4] = pk;
    }
    for (int i = t; i < K1 * 64; i += stride) {            // W1 [k][n] -> [n][k]
        int k = i >> 6, n = i & 63;
        _Float16 h = (_Float16)W1[i];
        ws_w1t[n * K1 + k] = __builtin_bit_cast(unsigned short, h);
    }
    for (int i = t; i < K2 * 64; i += stride) {            // W2 [k][n] -> [n][k]
        int k = i >> 6, n = i & 63;
        _Float16 h = (_Float16)W2[i];
        ws_w2t[n * K2 + k] = __builtin_bit_cast(unsigned short, h);
    }
    for (int i = t; i < 16 * D_GLOB; i += stride) {        // u
        _Float16 h = (_Float16)u[i];
        ws_ub[i] = __builtin_bit_cast(unsigned short, h);
    }
}

// ---------------------------------------------------------------------------
// Edge kernel (32x32x16 MFMA, SWAPPED operands): msg = relu(feat @ W1 + b1).
// mfma(Wf, feat) -> D[ch][edge]: row=(r&3)+8*(r>>2)+4*half is the CHANNEL,
// col=lane&31 is the EDGE. Even/odd r are adjacent channels -> pack pairs
// into global_atomic_pk_add_f16 (32M RMWs instead of 64M f32 atomics).
// agg f16 row d sits at byte offset d*256 of d_out (pre-zeroed).
// ---------------------------------------------------------------------------
__global__ __launch_bounds__(256, 4) void edge_kernel(
    const unsigned short* __restrict__ xb, const int* __restrict__ ei,
    const float* __restrict__ ea, const unsigned short* __restrict__ ub,
    const int* __restrict__ batch, const unsigned short* __restrict__ W1t,
    const float* __restrict__ b1, float* __restrict__ out)
{
    __shared__ __align__(16) unsigned short smem[64 * FS]; // 25600 B
    __shared__ int s_dst[64];
    __shared__ int s_src[64];
    __shared__ int s_b[64];

    const int tid  = threadIdx.x;
    const int lane = tid & 63;
    const int wv   = tid >> 6;
    const int tile = blockIdx.x;
    const int eh   = wv >> 1;
    const int nh   = wv & 1;
    const int col  = lane & 31;
    const int half = lane >> 5;

    if (tid < 64) {
        int e = tile * 64 + tid;
        int d = ei[N_EDGES + e];            // dst = edge_index[1]
        s_dst[tid] = d;
        s_src[tid] = ei[e];                 // src = edge_index[0]
        s_b[tid]   = batch[d];
    }

    // W fragments (A operand after swap): lane holds W1t[ch=nh*32+col][k]
    f16x8 Wf[12];
    #pragma unroll
    for (int s = 0; s < 12; ++s)
        Wf[s] = __builtin_bit_cast(f16x8,
            *(const ushort8_t*)&W1t[(nh*32 + col) * K1 + s*16 + half*8]);

    // Per-lane bias values for its 16 channels: nh*32 + 4*half + 8*g + j
    float bvf[16];
    #pragma unroll
    for (int g = 0; g < 4; ++g) {
        float4 t = *(const float4*)&b1[nh*32 + half*4 + g*8];
        bvf[g*4+0] = t.x; bvf[g*4+1] = t.y; bvf[g*4+2] = t.z; bvf[g*4+3] = t.w;
    }

    __syncthreads();

    // Gather: 64 edges x 24 16B-chunks of f16 (x[dst]:8 | x[src]:8 | ea:4 | u:4)
    const float4* ea4 = (const float4*)ea;
    for (int q = tid; q < 64 * 24; q += 256) {
        int el = q / 24;
        int c  = q - el * 24;
        uint4 pk;
        if (c < 8)       pk = *(const uint4*)&xb[s_dst[el] * 64 + c * 8];
        else if (c < 16) pk = *(const uint4*)&xb[s_src[el] * 64 + (c - 8) * 8];
        else if (c < 20) {
            float4 v0 = ea4[(tile*64 + el) * 8 + (c - 16) * 2 + 0];
            float4 v1 = ea4[(tile*64 + el) * 8 + (c - 16) * 2 + 1];
            pk.x = pack_f2(v0.x, v0.y); pk.y = pack_f2(v0.z, v0.w);
            pk.z = pack_f2(v1.x, v1.y); pk.w = pack_f2(v1.z, v1.w);
        } else           pk = *(const uint4*)&ub[s_b[el] * 32 + (c - 20) * 8];
        *(uint4*)&smem[el * FS + c * 8] = pk;
    }
    __syncthreads();

    // Compute: feat as B operand: lane holds feat[edge=eh*32+col][k]
    floatx16 acc = {0,0,0,0,0,0,0,0,0,0,0,0,0,0,0,0};
    #pragma unroll
    for (int s = 0; s < 12; ++s) {
        f16x8 a = __builtin_bit_cast(f16x8,
            *(const ushort8_t*)&smem[(eh*32 + col) * FS + s*16 + half*8]);
        acc = __builtin_amdgcn_mfma_f32_32x32x16_f16(Wf[s], a, acc, 0, 0, 0);
    }

    // Epilogue: one edge per lane; 8 packed f16 atomics cover 16 channels.
    const int e = eh*32 + col;
    unsigned short* arow = (unsigned short*)out + (size_t)s_dst[e] * 128;
    #pragma unroll
    for (int r = 0; r < 16; r += 2) {
        float v0 = acc[r]   + bvf[(r>>2)*4 + (r&3)];
        float v1 = acc[r+1] + bvf[(r>>2)*4 + (r&3) + 1];
        v0 = v0 > 0.f ? v0 : 0.f;
        v1 = v1 > 0.f ? v1 : 0.f;
        unsigned pk = pack_f2(v0, v1);
        int ch = nh*32 + half*4 + (r>>2)*8 + (r&3);   // even -> dword aligned
        asm volatile("global_atomic_pk_add_f16 %0, %1, off"
                     :: "v"(arow + ch), "v"(pk) : "memory");
    }
}

// ---------------------------------------------------------------------------
// Node kernel (32x32x16 MFMA): out = relu([x, agg, u[batch]] @ W2 + b2)
// agg read f16 from the first 128 B of each out row; in-place, row-exclusive
// per block. One 64-node tile per block (tail guarded).
// ---------------------------------------------------------------------------
__global__ __launch_bounds__(256, 4) void node_kernel(
    const unsigned short* __restrict__ xb, const unsigned short* __restrict__ ub,
    const int* __restrict__ batch, const unsigned short* __restrict__ W2t,
    const float* __restrict__ b2, float* __restrict__ out)
{
    __shared__ __align__(16) unsigned short smem[64 * FS];
    __shared__ int s_b[64];

    const int tid  = threadIdx.x;
    const int lane = tid & 63;
    const int wv   = tid >> 6;
    const int base = blockIdx.x * 64;
    const int eh   = wv >> 1;
    const int nh   = wv & 1;
    const int col  = lane & 31;
    const int half = lane >> 5;

    if (tid < 64) {
        int n = base + tid;
        s_b[tid] = (n < N_NODES) ? batch[n] : 0;
    }

    f16x8 Bf[10];
    #pragma unroll
    for (int s = 0; s < 10; ++s)
        Bf[s] = __builtin_bit_cast(f16x8,
            *(const ushort8_t*)&W2t[(nh*32 + col) * K2 + s*16 + half*8]);
    const float b2v = b2[nh*32 + col];

    __syncthreads();

    // Gather: 64 nodes x 20 16B-chunks (x:8 | agg:8 | u:4)
    const unsigned short* aggb = (const unsigned short*)out;
    for (int q = tid; q < 64 * 20; q += 256) {
        int nl = q / 20;
        int c  = q - nl * 20;
        int n  = base + nl;
        uint4 pk;
        if (n >= N_NODES) pk = uint4{0, 0, 0, 0};
        else if (c < 8)   pk = *(const uint4*)&xb[n * 64 + c * 8];
        else if (c < 16)  pk = *(const uint4*)&aggb[(size_t)n * 128 + (c - 8) * 8];
        else              pk = *(const uint4*)&ub[s_b[nl] * 32 + (c - 16) * 8];
        *(uint4*)&smem[nl * FS + c * 8] = pk;
    }
    __syncthreads();

    floatx16 acc = {0,0,0,0,0,0,0,0,0,0,0,0,0,0,0,0};
    #pragma unroll
    for (int s = 0; s < 10; ++s) {
        f16x8 a = __builtin_bit_cast(f16x8,
            *(const ushort8_t*)&smem[(eh*32 + col) * FS + s*16 + half*8]);
        acc = __builtin_amdgcn_mfma_f32_32x32x16_f16(a, Bf[s], acc, 0, 0, 0);
    }

    #pragma unroll
    for (int r = 0; r < 16; ++r) {
        int n = base + eh*32 + (r & 3) + 8*(r >> 2) + 4*half;
        if (n < N_NODES) {
            float vv = acc[r] + b2v;
            out[n * 64 + nh*32 + col] = vv > 0.f ? vv : 0.f;
        }
    }
}

extern "C" void kernel_launch(void* const* d_in, const int* in_sizes, int n_in,
                              void* d_out, int out_size, void* d_ws, size_t ws_size,
                              hipStream_t stream) {
    const float* x     = (const float*)d_in[0];
    const int*   ei    = (const int*)d_in[1];
    const float* ea    = (const float*)d_in[2];
    const float* u     = (const float*)d_in[3];
    const int*   batch = (const int*)d_in[4];
    const float* W1    = (const float*)d_in[5];
    const float* b1    = (const float*)d_in[6];
    const float* W2    = (const float*)d_in[7];
    const float* b2    = (const float*)d_in[8];
    float* out = (float*)d_out;

    unsigned short* ws_w1t = (unsigned short*)((char*)d_ws + WS_W1T);
    unsigned short* ws_w2t = (unsigned short*)((char*)d_ws + WS_W2T);
    unsigned short* ws_ub  = (unsigned short*)((char*)d_ws + WS_UB);
    unsigned short* ws_xb  = (unsigned short*)((char*)d_ws + WS_XB);

    // agg (f16) accumulates in the low half of each d_out row; zero it all
    (void)hipMemsetAsync(out, 0, (size_t)out_size * sizeof(float), stream);

    prep_kernel<<<2048, 256, 0, stream>>>(x, u, W1, W2, ws_w1t, ws_w2t, ws_ub, ws_xb);
    edge_kernel<<<N_EDGES / 64, 256, 0, stream>>>(ws_xb, ei, ea, ws_ub, batch, ws_w1t, b1, out);
    node_kernel<<<(N_NODES + 63) / 64, 256, 0, stream>>>(ws_xb, ws_ub, batch, ws_w2t, b2, out);
}

// Round 3
// 942.608 us; speedup vs baseline: 1.1372x; 1.1372x over previous
//
#include <hip/hip_runtime.h>

// Problem constants (from reference)
constexpr int N_NODES = 100000;
constexpr int N_EDGES = 1000000;
constexpr int D_NODE  = 64;
constexpr int D_EDGE  = 32;
constexpr int D_GLOB  = 32;
constexpr int OUT_DIM = 64;
constexpr int K1 = 2*D_NODE + D_EDGE + D_GLOB; // 192
constexpr int K2 = D_NODE + OUT_DIM + D_GLOB;  // 160

typedef _Float16 f16x8 __attribute__((ext_vector_type(8)));
typedef unsigned short ushort8_t __attribute__((ext_vector_type(8)));
typedef float floatx16 __attribute__((ext_vector_type(16)));

// LDS feature-tile row stride (f16 elems): 400 B rows, 16B-aligned.
constexpr int FS = 200;

// d_ws layout (bytes), all 16B-aligned (~17.9 MB total):
//   [0,        24576)     W1t f16 [64][192]  (transposed: [n][k])
//   [24576,    45056)     W2t f16 [64][160]
//   [45056,    46080)     ub  f16 [16][32]
//   [46080,    12846080)  xb  f16 [100000][64]   (12.8 MB)
//   [12846080, 13370368)  cnt/cursor int[131072] (hist counts, then scatter cursors)
//   [13370368, 13894656)  starts int[131072]     (CSR row starts; starts[100000]=1M)
//   [13894656, 17894656)  sorted_e int[1000000]  (edge ids sorted by dst)
constexpr size_t WS_W1T   = 0;
constexpr size_t WS_W2T   = 24576;
constexpr size_t WS_UB    = 45056;
constexpr size_t WS_XB    = 46080;
constexpr size_t WS_CNT   = 12846080;
constexpr size_t WS_START = 13370368;
constexpr size_t WS_SORT  = 13894656;

__device__ inline unsigned pack_f2(float a, float b) {
    auto h = __builtin_amdgcn_cvt_pkrtz(a, b);    // v_cvt_pkrtz_f16_f32
    return __builtin_bit_cast(unsigned, h);
}

// ---------------------------------------------------------------------------
// Prep: f16-convert x, u; f16+transpose W1, W2; dst histogram (cnt pre-zeroed
// by hipMemsetAsync). Runs every launch (harness re-poisons d_ws).
// ---------------------------------------------------------------------------
__global__ __launch_bounds__(256) void prep_kernel(
    const float* __restrict__ x, const float* __restrict__ u,
    const float* __restrict__ W1, const float* __restrict__ W2,
    const int* __restrict__ ei, int* __restrict__ cnt,
    unsigned short* __restrict__ ws_w1t, unsigned short* __restrict__ ws_w2t,
    unsigned short* __restrict__ ws_ub, unsigned short* __restrict__ ws_xb)
{
    const int t = blockIdx.x * 256 + threadIdx.x;
    const int stride = gridDim.x * 256;
    const float4* x4 = (const float4*)x;
    for (int i = t; i < N_NODES * 16; i += stride) {       // x: 1.6M float4
        float4 v = x4[i];
        uint2 pk;
        pk.x = pack_f2(v.x, v.y);
        pk.y = pack_f2(v.z, v.w);
        *(uint2*)&ws_xb[i * 4] = pk;
    }
    for (int i = t; i < N_EDGES; i += stride)              // dst histogram
        atomicAdd(&cnt[ei[N_EDGES + i]], 1);
    for (int i = t; i < K1 * 64; i += stride) {            // W1 [k][n] -> [n][k]
        int k = i >> 6, n = i & 63;
        _Float16 h = (_Float16)W1[i];
        ws_w1t[n * K1 + k] = __builtin_bit_cast(unsigned short, h);
    }
    for (int i = t; i < K2 * 64; i += stride) {            // W2 [k][n] -> [n][k]
        int k = i >> 6, n = i & 63;
        _Float16 h = (_Float16)W2[i];
        ws_w2t[n * K2 + k] = __builtin_bit_cast(unsigned short, h);
    }
    for (int i = t; i < 16 * D_GLOB; i += stride) {        // u
        _Float16 h = (_Float16)u[i];
        ws_ub[i] = __builtin_bit_cast(unsigned short, h);
    }
}

// ---------------------------------------------------------------------------
// Scan: exclusive prefix sum over 100K counts, single block of 1024 threads,
// each owning 100 contiguous elements (region zero-padded to 131072 so no
// guards needed; threads past 100000 harmlessly write total into reserved
// space, which conveniently sets starts[100000] = N_EDGES).
// Writes starts[] (preserved CSR) and cursor[] (consumed by scatter).
// ---------------------------------------------------------------------------
__global__ __launch_bounds__(1024) void scan_kernel(
    int* __restrict__ cnt_cursor, int* __restrict__ starts)
{
    __shared__ int lds[1024];
    const int t = threadIdx.x;
    const int4* c4 = (const int4*)cnt_cursor;
    const int b4 = t * 25;                    // 25 int4 = 100 ints per thread
    int s = 0;
    #pragma unroll 5
    for (int j = 0; j < 25; ++j) {
        int4 v = c4[b4 + j];
        s += v.x + v.y + v.z + v.w;
    }
    lds[t] = s;
    __syncthreads();
    for (int off = 1; off < 1024; off <<= 1) {
        int v = (t >= off) ? lds[t - off] : 0;
        __syncthreads();
        lds[t] += v;
        __syncthreads();
    }
    int run = lds[t] - s;                     // exclusive offset for this thread
    #pragma unroll 5
    for (int j = 0; j < 25; ++j) {
        int4 v = c4[b4 + j];
        int4 st;
        st.x = run; run += v.x;
        st.y = run; run += v.y;
        st.z = run; run += v.z;
        st.w = run; run += v.w;
        ((int4*)starts)[b4 + j] = st;
        ((int4*)cnt_cursor)[b4 + j] = st;     // cursor starts at row start
    }
}

// ---------------------------------------------------------------------------
// Scatter: place edge ids into dst-sorted order via cursor atomics.
// ---------------------------------------------------------------------------
__global__ __launch_bounds__(256) void scatter_kernel(
    const int* __restrict__ ei, int* __restrict__ cursor,
    int* __restrict__ sorted_e)
{
    const int t = blockIdx.x * 256 + threadIdx.x;
    const int stride = gridDim.x * 256;
    for (int e = t; e < N_EDGES; e += stride) {
        int d = ei[N_EDGES + e];
        int pos = atomicAdd(&cursor[d], 1);
        sorted_e[pos] = e;
    }
}

// ---------------------------------------------------------------------------
// Fused kernel: one block owns 64 dst nodes. Streams its sorted incoming
// edges in 64-edge chunks: gather feats -> 32x32x16 MFMA (msg = feat@W1) ->
// bias+ReLU -> ds_add_f32 into LDS agg[64][64] (no global atomics at all).
// Then MLP2 in-block: feat2 = [x | agg | u] @ W2, ReLU, coalesced store.
// Next-chunk edge indices are software-pipelined (loads issued one chunk
// ahead so the 3-deep dependent chain hides under gather+MFMA).
// ---------------------------------------------------------------------------
__global__ __launch_bounds__(256, 3) void fused_kernel(
    const unsigned short* __restrict__ xb, const int* __restrict__ ei,
    const float* __restrict__ ea, const unsigned short* __restrict__ ub,
    const int* __restrict__ batch, const int* __restrict__ starts,
    const int* __restrict__ sorted_e,
    const unsigned short* __restrict__ W1t, const float* __restrict__ b1,
    const unsigned short* __restrict__ W2t, const float* __restrict__ b2,
    float* __restrict__ out)
{
    __shared__ __align__(16) unsigned short smem[64 * FS];  // 25600 B feat tile
    __shared__ __align__(16) float aggf[64 * 64];           // 16384 B agg tile
    __shared__ int s_e[64], s_dst[64], s_src[64], s_b[64];  // 1024 B

    const int tid  = threadIdx.x;
    const int lane = tid & 63;
    const int wv   = tid >> 6;
    const int nb0  = blockIdx.x * 64;
    const int eh   = wv >> 1;
    const int nh   = wv & 1;
    const int col  = lane & 31;
    const int half = lane >> 5;

    const int nb1 = (nb0 + 64 < N_NODES) ? nb0 + 64 : N_NODES;
    const int lo  = starts[nb0];
    const int hi  = starts[nb1];

    // Zero LDS agg accumulator
    #pragma unroll
    for (int j = 0; j < 16; ++j) aggf[tid * 16 + j] = 0.f;

    // W1 fragments (B operand): lane holds W1t[ch=nh*32+col][k]
    f16x8 Wf[12];
    #pragma unroll
    for (int s = 0; s < 12; ++s)
        Wf[s] = __builtin_bit_cast(f16x8,
            *(const ushort8_t*)&W1t[(nh*32 + col) * K1 + s*16 + half*8]);
    const float b1v = b1[nh*32 + col];

    // Prefetch chunk-0 indices into registers (tid<64)
    int r_e = 0, r_d = -1, r_s = 0, r_b = 0;
    if (tid < 64 && lo + tid < hi) {
        r_e = sorted_e[lo + tid];
        r_d = ei[N_EDGES + r_e];
        r_s = ei[r_e];
        r_b = batch[r_d];
    }

    const float4* ea4 = (const float4*)ea;

    for (int cs = lo; cs < hi; cs += 64) {
        const int m = (hi - cs < 64) ? hi - cs : 64;
        __syncthreads();                       // prev chunk readers done
        if (tid < 64) {
            s_e[tid] = r_e; s_dst[tid] = r_d; s_src[tid] = r_s; s_b[tid] = r_b;
            // issue next-chunk index chain (consumed next iteration)
            int cs2 = cs + 64;
            if (cs2 + tid < hi) {
                r_e = sorted_e[cs2 + tid];
                r_d = ei[N_EDGES + r_e];
                r_s = ei[r_e];
                r_b = batch[r_d];
            } else r_d = -1;
        }
        __syncthreads();                       // indices visible

        // Gather: 64 edges x 24 16B-chunks (x[dst]:8 | x[src]:8 | ea:4 | u:4)
        for (int q = tid; q < 64 * 24; q += 256) {
            int el = q / 24;
            int c  = q - el * 24;
            uint4 pk = {0, 0, 0, 0};
            if (el < m) {
                if (c < 8)       pk = *(const uint4*)&xb[(size_t)s_dst[el] * 64 + c * 8];
                else if (c < 16) pk = *(const uint4*)&xb[(size_t)s_src[el] * 64 + (c - 8) * 8];
                else if (c < 20) {
                    float4 v0 = ea4[(size_t)s_e[el] * 8 + (c - 16) * 2 + 0];
                    float4 v1 = ea4[(size_t)s_e[el] * 8 + (c - 16) * 2 + 1];
                    pk.x = pack_f2(v0.x, v0.y); pk.y = pack_f2(v0.z, v0.w);
                    pk.z = pack_f2(v1.x, v1.y); pk.w = pack_f2(v1.z, v1.w);
                } else           pk = *(const uint4*)&ub[s_b[el] * 32 + (c - 20) * 8];
            }
            *(uint4*)&smem[el * FS + c * 8] = pk;
        }
        __syncthreads();                       // feat visible

        // msg = feat @ W1 : D[edge][ch]
        floatx16 acc = {0,0,0,0,0,0,0,0,0,0,0,0,0,0,0,0};
        #pragma unroll
        for (int s = 0; s < 12; ++s) {
            f16x8 a = __builtin_bit_cast(f16x8,
                *(const ushort8_t*)&smem[(eh*32 + col) * FS + s*16 + half*8]);
            acc = __builtin_amdgcn_mfma_f32_32x32x16_f16(a, Wf[s], acc, 0, 0, 0);
        }

        // bias + ReLU + LDS segment-sum (dst-local row, conflict-free banks)
        #pragma unroll
        for (int r = 0; r < 16; ++r) {
            int row = eh*32 + (r & 3) + 8*(r >> 2) + 4*half;
            int d = s_dst[row];
            if (d >= 0) {
                float v = acc[r] + b1v;
                v = v > 0.f ? v : 0.f;
                atomicAdd(&aggf[(d - nb0) * 64 + nh*32 + col], v);
            }
        }
    }
    __syncthreads();                           // all agg adds done

    // ---- MLP2 phase: feat2 = [x | agg | u[batch]] ----
    if (tid < 64) {
        int n = nb0 + tid;
        s_b[tid] = (n < N_NODES) ? batch[n] : 0;
    }
    __syncthreads();

    for (int q = tid; q < 64 * 20; q += 256) {
        int nl = q / 20;
        int c  = q - nl * 20;
        int n  = nb0 + nl;
        uint4 pk = {0, 0, 0, 0};
        if (n < N_NODES) {
            if (c < 8)       pk = *(const uint4*)&xb[(size_t)n * 64 + c * 8];
            else if (c < 16) {
                float4 f0 = *(const float4*)&aggf[nl * 64 + (c - 8) * 8];
                float4 f1 = *(const float4*)&aggf[nl * 64 + (c - 8) * 8 + 4];
                pk.x = pack_f2(f0.x, f0.y); pk.y = pack_f2(f0.z, f0.w);
                pk.z = pack_f2(f1.x, f1.y); pk.w = pack_f2(f1.z, f1.w);
            } else           pk = *(const uint4*)&ub[s_b[nl] * 32 + (c - 16) * 8];
        }
        *(uint4*)&smem[nl * FS + c * 8] = pk;
    }
    __syncthreads();

    f16x8 Bf2[10];
    #pragma unroll
    for (int s = 0; s < 10; ++s)
        Bf2[s] = __builtin_bit_cast(f16x8,
            *(const ushort8_t*)&W2t[(nh*32 + col) * K2 + s*16 + half*8]);
    const float b2v = b2[nh*32 + col];

    floatx16 acc2 = {0,0,0,0,0,0,0,0,0,0,0,0,0,0,0,0};
    #pragma unroll
    for (int s = 0; s < 10; ++s) {
        f16x8 a = __builtin_bit_cast(f16x8,
            *(const ushort8_t*)&smem[(eh*32 + col) * FS + s*16 + half*8]);
        acc2 = __builtin_amdgcn_mfma_f32_32x32x16_f16(a, Bf2[s], acc2, 0, 0, 0);
    }

    #pragma unroll
    for (int r = 0; r < 16; ++r) {
        int n = nb0 + eh*32 + (r & 3) + 8*(r >> 2) + 4*half;
        if (n < N_NODES) {
            float vv = acc2[r] + b2v;
            out[(size_t)n * 64 + nh*32 + col] = vv > 0.f ? vv : 0.f;
        }
    }
}

extern "C" void kernel_launch(void* const* d_in, const int* in_sizes, int n_in,
                              void* d_out, int out_size, void* d_ws, size_t ws_size,
                              hipStream_t stream) {
    const float* x     = (const float*)d_in[0];
    const int*   ei    = (const int*)d_in[1];
    const float* ea    = (const float*)d_in[2];
    const float* u     = (const float*)d_in[3];
    const int*   batch = (const int*)d_in[4];
    const float* W1    = (const float*)d_in[5];
    const float* b1    = (const float*)d_in[6];
    const float* W2    = (const float*)d_in[7];
    const float* b2    = (const float*)d_in[8];
    float* out = (float*)d_out;

    unsigned short* ws_w1t = (unsigned short*)((char*)d_ws + WS_W1T);
    unsigned short* ws_w2t = (unsigned short*)((char*)d_ws + WS_W2T);
    unsigned short* ws_ub  = (unsigned short*)((char*)d_ws + WS_UB);
    unsigned short* ws_xb  = (unsigned short*)((char*)d_ws + WS_XB);
    int* cnt    = (int*)((char*)d_ws + WS_CNT);
    int* starts = (int*)((char*)d_ws + WS_START);
    int* sorted = (int*)((char*)d_ws + WS_SORT);

    // zero histogram region (padded to 131072 ints so scan needs no guards)
    (void)hipMemsetAsync(cnt, 0, 524288, stream);

    prep_kernel<<<2048, 256, 0, stream>>>(x, u, W1, W2, ei, cnt,
                                          ws_w1t, ws_w2t, ws_ub, ws_xb);
    scan_kernel<<<1, 1024, 0, stream>>>(cnt, starts);
    scatter_kernel<<<2048, 256, 0, stream>>>(ei, cnt, sorted);
    fused_kernel<<<(N_NODES + 63) / 64, 256, 0, stream>>>(
        ws_xb, ei, ea, ws_ub, batch, starts, sorted,
        ws_w1t, b1, ws_w2t, b2, out);
}

// Round 4
// 437.345 us; speedup vs baseline: 2.4510x; 2.1553x over previous
//
#include <hip/hip_runtime.h>

// Problem constants (from reference)
constexpr int N_NODES = 100000;
constexpr int N_EDGES = 1000000;
constexpr int D_NODE  = 64;
constexpr int D_EDGE  = 32;
constexpr int D_GLOB  = 32;
constexpr int OUT_DIM = 64;
constexpr int K1 = 2*D_NODE + D_EDGE + D_GLOB; // 192
constexpr int K2 = D_NODE + OUT_DIM + D_GLOB;  // 160

typedef _Float16 f16x8 __attribute__((ext_vector_type(8)));
typedef unsigned short ushort8_t __attribute__((ext_vector_type(8)));
typedef float floatx16 __attribute__((ext_vector_type(16)));

// LDS feature-tile row stride (f16 elems): 400 B rows, 16B-aligned.
constexpr int FS = 200;

// d_ws layout (bytes), all 16B-aligned:
//   [0,     24576)  W1t f16 [64][192]   (transposed: [n][k])
//   [24576, 45056)  W2t f16 [64][160]
//   [45056, 46080)  ub  f16 [16][32]
//   [46080, ...  )  xb  f16 [100000][64]  (12.8 MB)
// agg (f16 [100000][64]) lives INSIDE d_out: row n occupies the first
// 128 B of out row n (256 B). Block-exclusive in node_kernel -> no race.
constexpr size_t WS_W1T = 0;
constexpr size_t WS_W2T = 24576;
constexpr size_t WS_UB  = 45056;
constexpr size_t WS_XB  = 46080;

__device__ inline unsigned pack_f2(float a, float b) {
    auto h = __builtin_amdgcn_cvt_pkrtz(a, b);    // v_cvt_pkrtz_f16_f32
    return __builtin_bit_cast(unsigned, h);
}

// ---------------------------------------------------------------------------
// Prep: f16-convert x, u; f16+transpose W1, W2 into d_ws. Runs every launch
// (harness re-poisons d_ws).
// ---------------------------------------------------------------------------
__global__ __launch_bounds__(256) void prep_kernel(
    const float* __restrict__ x, const float* __restrict__ u,
    const float* __restrict__ W1, const float* __restrict__ W2,
    unsigned short* __restrict__ ws_w1t, unsigned short* __restrict__ ws_w2t,
    unsigned short* __restrict__ ws_ub, unsigned short* __restrict__ ws_xb)
{
    const int t = blockIdx.x * 256 + threadIdx.x;
    const int stride = gridDim.x * 256;
    const float4* x4 = (const float4*)x;
    for (int i = t; i < N_NODES * 16; i += stride) {       // x: 1.6M float4
        float4 v = x4[i];
        uint2 pk;
        pk.x = pack_f2(v.x, v.y);
        pk.y = pack_f2(v.z, v.w);
        *(uint2*)&ws_xb[i * 4] = pk;
    }
    for (int i = t; i < K1 * 64; i += stride) {            // W1 [k][n] -> [n][k]
        int k = i >> 6, n = i & 63;
        _Float16 h = (_Float16)W1[i];
        ws_w1t[n * K1 + k] = __builtin_bit_cast(unsigned short, h);
    }
    for (int i = t; i < K2 * 64; i += stride) {            // W2 [k][n] -> [n][k]
        int k = i >> 6, n = i & 63;
        _Float16 h = (_Float16)W2[i];
        ws_w2t[n * K2 + k] = __builtin_bit_cast(unsigned short, h);
    }
    for (int i = t; i < 16 * D_GLOB; i += stride) {        // u
        _Float16 h = (_Float16)u[i];
        ws_ub[i] = __builtin_bit_cast(unsigned short, h);
    }
}

// ---------------------------------------------------------------------------
// Edge kernel (32x32x16 MFMA, R0 orientation): msg = relu(feat @ W1 + b1),
// D[edge][ch]. New epilogue: msg tile round-trips through LDS (f32 64x64,
// reusing the feat buffer), then each wave re-reads it TRANSPOSED so one
// pk_add_f16 instruction covers all 64 channels of exactly 2 dst rows
// (2 rows x 128B = 4 lines/instr, R0-grade locality, HALF the RMW ops).
// agg f16 row d sits at byte offset d*256 of d_out (pre-zeroed).
// ---------------------------------------------------------------------------
__global__ __launch_bounds__(256, 4) void edge_kernel(
    const unsigned short* __restrict__ xb, const int* __restrict__ ei,
    const float* __restrict__ ea, const unsigned short* __restrict__ ub,
    const int* __restrict__ batch, const unsigned short* __restrict__ W1t,
    const float* __restrict__ b1, float* __restrict__ out)
{
    __shared__ __align__(16) unsigned short smem[64 * FS]; // 25600 B (feat, then f32 msg[64][64])
    __shared__ int s_dst[64];
    __shared__ int s_src[64];
    __shared__ int s_b[64];

    const int tid  = threadIdx.x;
    const int lane = tid & 63;
    const int wv   = tid >> 6;
    const int tile = blockIdx.x;
    const int eh   = wv >> 1;
    const int nh   = wv & 1;
    const int col  = lane & 31;
    const int half = lane >> 5;

    if (tid < 64) {
        int e = tile * 64 + tid;
        int d = ei[N_EDGES + e];            // dst = edge_index[1]
        s_dst[tid] = d;
        s_src[tid] = ei[e];                 // src = edge_index[0]
        s_b[tid]   = batch[d];
    }

    // B fragments: B[k][n], n = nh*32+col, k = s*16 + half*8 + j
    f16x8 Wf[12];
    #pragma unroll
    for (int s = 0; s < 12; ++s)
        Wf[s] = __builtin_bit_cast(f16x8,
            *(const ushort8_t*)&W1t[(nh*32 + col) * K1 + s*16 + half*8]);

    // Epilogue channel-pair for this lane (covers ch 2*(lane&31), +1)
    const int chp = (lane & 31) * 2;
    const float2 bv = *(const float2*)&b1[chp];

    __syncthreads();

    // Gather: 64 edges x 24 16B-chunks of f16 (x[dst]:8 | x[src]:8 | ea:4 | u:4)
    const float4* ea4 = (const float4*)ea;
    for (int q = tid; q < 64 * 24; q += 256) {
        int el = q / 24;
        int c  = q - el * 24;
        uint4 pk;
        if (c < 8)       pk = *(const uint4*)&xb[s_dst[el] * 64 + c * 8];
        else if (c < 16) pk = *(const uint4*)&xb[s_src[el] * 64 + (c - 8) * 8];
        else if (c < 20) {
            float4 v0 = ea4[(tile*64 + el) * 8 + (c - 16) * 2 + 0];
            float4 v1 = ea4[(tile*64 + el) * 8 + (c - 16) * 2 + 1];
            pk.x = pack_f2(v0.x, v0.y); pk.y = pack_f2(v0.z, v0.w);
            pk.z = pack_f2(v1.x, v1.y); pk.w = pack_f2(v1.z, v1.w);
        } else           pk = *(const uint4*)&ub[s_b[el] * 32 + (c - 20) * 8];
        *(uint4*)&smem[el * FS + c * 8] = pk;
    }
    __syncthreads();

    // Compute: A rows = edges (eh*32 + col), B cols = channels -> D[edge][ch]
    floatx16 acc = {0,0,0,0,0,0,0,0,0,0,0,0,0,0,0,0};
    #pragma unroll
    for (int s = 0; s < 12; ++s) {
        f16x8 a = __builtin_bit_cast(f16x8,
            *(const ushort8_t*)&smem[(eh*32 + col) * FS + s*16 + half*8]);
        acc = __builtin_amdgcn_mfma_f32_32x32x16_f16(a, Wf[s], acc, 0, 0, 0);
    }

    // Stage msg tile to LDS (f32 [64 edge][64 ch]); C layout:
    // edge = eh*32 + (r&3)+8*(r>>2)+4*half, ch = nh*32+col.
    __syncthreads();                       // all waves done reading feat tile
    float* smemf = (float*)smem;
    #pragma unroll
    for (int r = 0; r < 16; ++r) {
        int e = eh*32 + (r & 3) + 8*(r >> 2) + 4*half;
        smemf[e * 64 + nh*32 + col] = acc[r];
    }
    __syncthreads();

    // Transposed epilogue: wave wv owns edges [wv*16, wv*16+16); per iter the
    // 64 lanes cover 2 edge rows x 32 channel-pairs -> 2 agg rows, 4 lines.
    #pragma unroll
    for (int it = 0; it < 8; ++it) {
        int e = wv*16 + it*2 + half;
        float2 m = *(const float2*)&smemf[e * 64 + chp];
        float v0 = m.x + bv.x; v0 = v0 > 0.f ? v0 : 0.f;
        float v1 = m.y + bv.y; v1 = v1 > 0.f ? v1 : 0.f;
        unsigned pk = pack_f2(v0, v1);
        unsigned short* p = (unsigned short*)out + (size_t)s_dst[e] * 128 + chp;
        asm volatile("global_atomic_pk_add_f16 %0, %1, off"
                     :: "v"(p), "v"(pk) : "memory");
    }
}

// ---------------------------------------------------------------------------
// Node kernel (32x32x16 MFMA): out = relu([x, agg, u[batch]] @ W2 + b2)
// agg read f16 from the first 128 B of each out row; in-place, row-exclusive
// per block. One 64-node tile per block (tail guarded).
// ---------------------------------------------------------------------------
__global__ __launch_bounds__(256, 4) void node_kernel(
    const unsigned short* __restrict__ xb, const unsigned short* __restrict__ ub,
    const int* __restrict__ batch, const unsigned short* __restrict__ W2t,
    const float* __restrict__ b2, float* __restrict__ out)
{
    __shared__ __align__(16) unsigned short smem[64 * FS];
    __shared__ int s_b[64];

    const int tid  = threadIdx.x;
    const int lane = tid & 63;
    const int wv   = tid >> 6;
    const int base = blockIdx.x * 64;
    const int eh   = wv >> 1;
    const int nh   = wv & 1;
    const int col  = lane & 31;
    const int half = lane >> 5;

    if (tid < 64) {
        int n = base + tid;
        s_b[tid] = (n < N_NODES) ? batch[n] : 0;
    }

    f16x8 Bf[10];
    #pragma unroll
    for (int s = 0; s < 10; ++s)
        Bf[s] = __builtin_bit_cast(f16x8,
            *(const ushort8_t*)&W2t[(nh*32 + col) * K2 + s*16 + half*8]);
    const float b2v = b2[nh*32 + col];

    __syncthreads();

    // Gather: 64 nodes x 20 16B-chunks (x:8 | agg:8 | u:4)
    const unsigned short* aggb = (const unsigned short*)out;
    for (int q = tid; q < 64 * 20; q += 256) {
        int nl = q / 20;
        int c  = q - nl * 20;
        int n  = base + nl;
        uint4 pk;
        if (n >= N_NODES) pk = uint4{0, 0, 0, 0};
        else if (c < 8)   pk = *(const uint4*)&xb[n * 64 + c * 8];
        else if (c < 16)  pk = *(const uint4*)&aggb[(size_t)n * 128 + (c - 8) * 8];
        else              pk = *(const uint4*)&ub[s_b[nl] * 32 + (c - 16) * 8];
        *(uint4*)&smem[nl * FS + c * 8] = pk;
    }
    __syncthreads();

    floatx16 acc = {0,0,0,0,0,0,0,0,0,0,0,0,0,0,0,0};
    #pragma unroll
    for (int s = 0; s < 10; ++s) {
        f16x8 a = __builtin_bit_cast(f16x8,
            *(const ushort8_t*)&smem[(eh*32 + col) * FS + s*16 + half*8]);
        acc = __builtin_amdgcn_mfma_f32_32x32x16_f16(a, Bf[s], acc, 0, 0, 0);
    }

    #pragma unroll
    for (int r = 0; r < 16; ++r) {
        int n = base + eh*32 + (r & 3) + 8*(r >> 2) + 4*half;
        if (n < N_NODES) {
            float vv = acc[r] + b2v;
            out[n * 64 + nh*32 + col] = vv > 0.f ? vv : 0.f;
        }
    }
}

extern "C" void kernel_launch(void* const* d_in, const int* in_sizes, int n_in,
                              void* d_out, int out_size, void* d_ws, size_t ws_size,
                              hipStream_t stream) {
    const float* x     = (const float*)d_in[0];
    const int*   ei    = (const int*)d_in[1];
    const float* ea    = (const float*)d_in[2];
    const float* u     = (const float*)d_in[3];
    const int*   batch = (const int*)d_in[4];
    const float* W1    = (const float*)d_in[5];
    const float* b1    = (const float*)d_in[6];
    const float* W2    = (const float*)d_in[7];
    const float* b2    = (const float*)d_in[8];
    float* out = (float*)d_out;

    unsigned short* ws_w1t = (unsigned short*)((char*)d_ws + WS_W1T);
    unsigned short* ws_w2t = (unsigned short*)((char*)d_ws + WS_W2T);
    unsigned short* ws_ub  = (unsigned short*)((char*)d_ws + WS_UB);
    unsigned short* ws_xb  = (unsigned short*)((char*)d_ws + WS_XB);

    // agg (f16) accumulates in the low half of each d_out row; zero it all
    (void)hipMemsetAsync(out, 0, (size_t)out_size * sizeof(float), stream);

    prep_kernel<<<2048, 256, 0, stream>>>(x, u, W1, W2, ws_w1t, ws_w2t, ws_ub, ws_xb);
    edge_kernel<<<N_EDGES / 64, 256, 0, stream>>>(ws_xb, ei, ea, ws_ub, batch, ws_w1t, b1, out);
    node_kernel<<<(N_NODES + 63) / 64, 256, 0, stream>>>(ws_xb, ws_ub, batch, ws_w2t, b2, out);
}

// Round 5
// 363.158 us; speedup vs baseline: 2.9517x; 1.2043x over previous
//
#include <hip/hip_runtime.h>

// Problem constants (from reference)
constexpr int N_NODES = 100000;
constexpr int N_EDGES = 1000000;
constexpr int D_NODE  = 64;
constexpr int D_EDGE  = 32;
constexpr int D_GLOB  = 32;
constexpr int OUT_DIM = 64;
constexpr int K1 = 2*D_NODE + D_EDGE + D_GLOB; // 192
constexpr int K2 = D_NODE + OUT_DIM + D_GLOB;  // 160

typedef _Float16 f16x8 __attribute__((ext_vector_type(8)));
typedef unsigned short ushort8_t __attribute__((ext_vector_type(8)));
typedef float floatx16 __attribute__((ext_vector_type(16)));

// LDS feature-tile row stride (f16 elems): 400 B rows, 16B-aligned.
constexpr int FS = 200;

// d_ws layout (bytes), all 16B-aligned:
//   [0,     24576)  W1t f16 [64][192]   (transposed: [n][k])
//   [24576, 45056)  W2t f16 [64][160]
//   [45056, 46080)  ub  f16 [16][32]
//   [46080, ...  )  xb  f16 [100000][64]  (12.8 MB)
// agg (f16 [100000][64]) lives INSIDE d_out: row n occupies the first
// 128 B of out row n (256 B). Block-exclusive in node_kernel -> no race.
constexpr size_t WS_W1T = 0;
constexpr size_t WS_W2T = 24576;
constexpr size_t WS_UB  = 45056;
constexpr size_t WS_XB  = 46080;

__device__ inline unsigned pack_f2(float a, float b) {
    auto h = __builtin_amdgcn_cvt_pkrtz(a, b);    // v_cvt_pkrtz_f16_f32
    return __builtin_bit_cast(unsigned, h);
}

// ---------------------------------------------------------------------------
// Prep: f16-convert x, u; f16+transpose W1, W2 into d_ws. Runs every launch
// (harness re-poisons d_ws).
// ---------------------------------------------------------------------------
__global__ __launch_bounds__(256) void prep_kernel(
    const float* __restrict__ x, const float* __restrict__ u,
    const float* __restrict__ W1, const float* __restrict__ W2,
    unsigned short* __restrict__ ws_w1t, unsigned short* __restrict__ ws_w2t,
    unsigned short* __restrict__ ws_ub, unsigned short* __restrict__ ws_xb)
{
    const int t = blockIdx.x * 256 + threadIdx.x;
    const int stride = gridDim.x * 256;
    const float4* x4 = (const float4*)x;
    for (int i = t; i < N_NODES * 16; i += stride) {       // x: 1.6M float4
        float4 v = x4[i];
        uint2 pk;
        pk.x = pack_f2(v.x, v.y);
        pk.y = pack_f2(v.z, v.w);
        *(uint2*)&ws_xb[i * 4] = pk;
    }
    for (int i = t; i < K1 * 64; i += stride) {            // W1 [k][n] -> [n][k]
        int k = i >> 6, n = i & 63;
        _Float16 h = (_Float16)W1[i];
        ws_w1t[n * K1 + k] = __builtin_bit_cast(unsigned short, h);
    }
    for (int i = t; i < K2 * 64; i += stride) {            // W2 [k][n] -> [n][k]
        int k = i >> 6, n = i & 63;
        _Float16 h = (_Float16)W2[i];
        ws_w2t[n * K2 + k] = __builtin_bit_cast(unsigned short, h);
    }
    for (int i = t; i < 16 * D_GLOB; i += stride) {        // u
        _Float16 h = (_Float16)u[i];
        ws_ub[i] = __builtin_bit_cast(unsigned short, h);
    }
}

// ---------------------------------------------------------------------------
// Edge kernel (32x32x16 MFMA, R0 orientation): msg = relu(feat @ W1 + b1),
// D[edge][ch]. Epilogue: msg tile round-trips through LDS (f32 64x64,
// reusing the feat buffer), then each wave re-reads it TRANSPOSED so one
// pk_add_f16 instruction covers all 64 channels of exactly 2 dst rows
// (2 rows x 128B = 2 lines/instr, R0-grade locality, HALF the RMW ops).
// ea gather is index-independent -> issued BEFORE the index barrier.
// 6 blocks/CU (LDS-capped) for latency overlap across blocks.
// ---------------------------------------------------------------------------
__global__ __launch_bounds__(256, 6) void edge_kernel(
    const unsigned short* __restrict__ xb, const int* __restrict__ ei,
    const float* __restrict__ ea, const unsigned short* __restrict__ ub,
    const int* __restrict__ batch, const unsigned short* __restrict__ W1t,
    const float* __restrict__ b1, float* __restrict__ out)
{
    __shared__ __align__(16) unsigned short smem[64 * FS]; // 25600 B (feat, then f32 msg[64][64])
    __shared__ int s_dst[64];
    __shared__ int s_src[64];
    __shared__ int s_b[64];

    const int tid  = threadIdx.x;
    const int lane = tid & 63;
    const int wv   = tid >> 6;
    const int tile = blockIdx.x;
    const int eh   = wv >> 1;
    const int nh   = wv & 1;
    const int col  = lane & 31;
    const int half = lane >> 5;
    const float4* ea4 = (const float4*)ea;

    if (tid < 64) {
        int e = tile * 64 + tid;
        int d = ei[N_EDGES + e];            // dst = edge_index[1]
        s_dst[tid] = d;
        s_src[tid] = ei[e];                 // src = edge_index[0]
        s_b[tid]   = batch[d];
    }

    // ea chunks depend only on tile: issue before the index barrier.
    // 256 threads x 1 chunk: el = tid>>2, c = tid&3; K slots [128,160).
    {
        int el = tid >> 2, c = tid & 3;
        float4 v0 = ea4[(tile*64 + el) * 8 + c * 2 + 0];
        float4 v1 = ea4[(tile*64 + el) * 8 + c * 2 + 1];
        uint4 pk;
        pk.x = pack_f2(v0.x, v0.y); pk.y = pack_f2(v0.z, v0.w);
        pk.z = pack_f2(v1.x, v1.y); pk.w = pack_f2(v1.z, v1.w);
        *(uint4*)&smem[el * FS + (16 + c) * 8] = pk;
    }

    // B fragments: B[k][n], n = nh*32+col, k = s*16 + half*8 + j
    f16x8 Wf[12];
    #pragma unroll
    for (int s = 0; s < 12; ++s)
        Wf[s] = __builtin_bit_cast(f16x8,
            *(const ushort8_t*)&W1t[(nh*32 + col) * K1 + s*16 + half*8]);

    // Epilogue channel-pair for this lane (covers ch 2*(lane&31), +1)
    const int chp = (lane & 31) * 2;
    const float2 bv = *(const float2*)&b1[chp];

    __syncthreads();                        // indices visible

    // Gather remaining 20 chunks/edge (x[dst]:8 | x[src]:8 | u:4), 5/thread.
    // K slots: x_dst [0,64), x_src [64,128), u [160,192).
    for (int q = tid; q < 64 * 20; q += 256) {
        int el = q / 20;
        int c  = q - el * 20;
        uint4 pk;
        if (c < 8)       pk = *(const uint4*)&xb[s_dst[el] * 64 + c * 8];
        else if (c < 16) pk = *(const uint4*)&xb[s_src[el] * 64 + (c - 8) * 8];
        else             pk = *(const uint4*)&ub[s_b[el] * 32 + (c - 16) * 8];
        *(uint4*)&smem[el * FS + (c < 16 ? c : c + 4) * 8] = pk;
    }
    __syncthreads();                        // feat visible

    // Compute: A rows = edges (eh*32 + col), B cols = channels -> D[edge][ch]
    floatx16 acc = {0,0,0,0,0,0,0,0,0,0,0,0,0,0,0,0};
    #pragma unroll
    for (int s = 0; s < 12; ++s) {
        f16x8 a = __builtin_bit_cast(f16x8,
            *(const ushort8_t*)&smem[(eh*32 + col) * FS + s*16 + half*8]);
        acc = __builtin_amdgcn_mfma_f32_32x32x16_f16(a, Wf[s], acc, 0, 0, 0);
    }

    // Stage msg tile to LDS (f32 [64 edge][64 ch]); C layout:
    // edge = eh*32 + (r&3)+8*(r>>2)+4*half, ch = nh*32+col.
    __syncthreads();                       // all waves done reading feat tile
    float* smemf = (float*)smem;
    #pragma unroll
    for (int r = 0; r < 16; ++r) {
        int e = eh*32 + (r & 3) + 8*(r >> 2) + 4*half;
        smemf[e * 64 + nh*32 + col] = acc[r];
    }
    __syncthreads();

    // Transposed epilogue: wave wv owns edges [wv*16, wv*16+16); per iter the
    // 64 lanes cover 2 edge rows x 32 channel-pairs -> 2 agg rows, 2 lines.
    #pragma unroll
    for (int it = 0; it < 8; ++it) {
        int e = wv*16 + it*2 + half;
        float2 m = *(const float2*)&smemf[e * 64 + chp];
        float v0 = m.x + bv.x; v0 = v0 > 0.f ? v0 : 0.f;
        float v1 = m.y + bv.y; v1 = v1 > 0.f ? v1 : 0.f;
        unsigned pk = pack_f2(v0, v1);
        unsigned short* p = (unsigned short*)out + (size_t)s_dst[e] * 128 + chp;
        asm volatile("global_atomic_pk_add_f16 %0, %1, off"
                     :: "v"(p), "v"(pk) : "memory");
    }
}

// ---------------------------------------------------------------------------
// Node kernel (32x32x16 MFMA): out = relu([x, agg, u[batch]] @ W2 + b2)
// agg read f16 from the first 128 B of each out row; in-place, row-exclusive
// per block. One 64-node tile per block (tail guarded).
// ---------------------------------------------------------------------------
__global__ __launch_bounds__(256, 6) void node_kernel(
    const unsigned short* __restrict__ xb, const unsigned short* __restrict__ ub,
    const int* __restrict__ batch, const unsigned short* __restrict__ W2t,
    const float* __restrict__ b2, float* __restrict__ out)
{
    __shared__ __align__(16) unsigned short smem[64 * FS];
    __shared__ int s_b[64];

    const int tid  = threadIdx.x;
    const int lane = tid & 63;
    const int wv   = tid >> 6;
    const int base = blockIdx.x * 64;
    const int eh   = wv >> 1;
    const int nh   = wv & 1;
    const int col  = lane & 31;
    const int half = lane >> 5;

    if (tid < 64) {
        int n = base + tid;
        s_b[tid] = (n < N_NODES) ? batch[n] : 0;
    }

    f16x8 Bf[10];
    #pragma unroll
    for (int s = 0; s < 10; ++s)
        Bf[s] = __builtin_bit_cast(f16x8,
            *(const ushort8_t*)&W2t[(nh*32 + col) * K2 + s*16 + half*8]);
    const float b2v = b2[nh*32 + col];

    __syncthreads();

    // Gather: 64 nodes x 20 16B-chunks (x:8 | agg:8 | u:4)
    const unsigned short* aggb = (const unsigned short*)out;
    for (int q = tid; q < 64 * 20; q += 256) {
        int nl = q / 20;
        int c  = q - nl * 20;
        int n  = base + nl;
        uint4 pk;
        if (n >= N_NODES) pk = uint4{0, 0, 0, 0};
        else if (c < 8)   pk = *(const uint4*)&xb[n * 64 + c * 8];
        else if (c < 16)  pk = *(const uint4*)&aggb[(size_t)n * 128 + (c - 8) * 8];
        else              pk = *(const uint4*)&ub[s_b[nl] * 32 + (c - 16) * 8];
        *(uint4*)&smem[nl * FS + c * 8] = pk;
    }
    __syncthreads();

    floatx16 acc = {0,0,0,0,0,0,0,0,0,0,0,0,0,0,0,0};
    #pragma unroll
    for (int s = 0; s < 10; ++s) {
        f16x8 a = __builtin_bit_cast(f16x8,
            *(const ushort8_t*)&smem[(eh*32 + col) * FS + s*16 + half*8]);
        acc = __builtin_amdgcn_mfma_f32_32x32x16_f16(a, Bf[s], acc, 0, 0, 0);
    }

    #pragma unroll
    for (int r = 0; r < 16; ++r) {
        int n = base + eh*32 + (r & 3) + 8*(r >> 2) + 4*half;
        if (n < N_NODES) {
            float vv = acc[r] + b2v;
            out[n * 64 + nh*32 + col] = vv > 0.f ? vv : 0.f;
        }
    }
}

extern "C" void kernel_launch(void* const* d_in, const int* in_sizes, int n_in,
                              void* d_out, int out_size, void* d_ws, size_t ws_size,
                              hipStream_t stream) {
    const float* x     = (const float*)d_in[0];
    const int*   ei    = (const int*)d_in[1];
    const float* ea    = (const float*)d_in[2];
    const float* u     = (const float*)d_in[3];
    const int*   batch = (const int*)d_in[4];
    const float* W1    = (const float*)d_in[5];
    const float* b1    = (const float*)d_in[6];
    const float* W2    = (const float*)d_in[7];
    const float* b2    = (const float*)d_in[8];
    float* out = (float*)d_out;

    unsigned short* ws_w1t = (unsigned short*)((char*)d_ws + WS_W1T);
    unsigned short* ws_w2t = (unsigned short*)((char*)d_ws + WS_W2T);
    unsigned short* ws_ub  = (unsigned short*)((char*)d_ws + WS_UB);
    unsigned short* ws_xb  = (unsigned short*)((char*)d_ws + WS_XB);

    // agg (f16) accumulates in the low half of each d_out row; zero it all
    (void)hipMemsetAsync(out, 0, (size_t)out_size * sizeof(float), stream);

    prep_kernel<<<2048, 256, 0, stream>>>(x, u, W1, W2, ws_w1t, ws_w2t, ws_ub, ws_xb);
    edge_kernel<<<N_EDGES / 64, 256, 0, stream>>>(ws_xb, ei, ea, ws_ub, batch, ws_w1t, b1, out);
    node_kernel<<<(N_NODES + 63) / 64, 256, 0, stream>>>(ws_xb, ws_ub, batch, ws_w2t, b2, out);
}